// Round 1
// baseline (1307.759 us; speedup 1.0000x reference)
//
#include <hip/hip_runtime.h>

#define NN 50000
#define NE 800000
#define HH 128

// ---------------------------------------------------------------------------
// Tiled fp32 GEMM: C[m][n] = act(bias[n] + sum_k A[m][k]*W[k][n])
// Tile 64x64, BK=16, 256 threads, 4x4 micro-tile per thread.
// N (columns launched) must be a multiple of 64; M guarded.
// ---------------------------------------------------------------------------
template<bool RELU>
__global__ __launch_bounds__(256)
void gemm_kernel(const float* __restrict__ A, int lda,
                 const float* __restrict__ W, int ldw,
                 const float* __restrict__ bias,
                 float* __restrict__ C, int ldc,
                 int M, int K)
{
    __shared__ float As[16][68];   // [k][m], pad 68 -> conflict-free + aligned b128
    __shared__ float Bs[16][64];   // [k][n]

    const int t  = threadIdx.x;
    const int m0 = blockIdx.y << 6;
    const int n0 = blockIdx.x << 6;
    const int tr = t >> 4;         // 0..15 -> rows tr*4 .. tr*4+3
    const int tc = t & 15;         // 0..15 -> cols tc*4 .. tc*4+3

    float acc[4][4] = {};

    for (int k0 = 0; k0 < K; k0 += 16) {
        // ---- load A tile (64 rows x 16 k) transposed into As[k][m]
        {
            const int k  = t & 15;
            const int mb = t >> 4;
#pragma unroll
            for (int i = 0; i < 4; ++i) {
                const int m  = mb + (i << 4);
                const int gm = m0 + m;
                float v = 0.f;
                if (gm < M) v = A[(size_t)gm * lda + k0 + k];
                As[k][m] = v;
            }
        }
        // ---- load B tile (16 k x 64 n) into Bs[k][n]
        {
            const int n  = t & 63;
            const int kb = t >> 6;
#pragma unroll
            for (int i = 0; i < 4; ++i) {
                const int k2 = kb + (i << 2);
                Bs[k2][n] = W[(size_t)(k0 + k2) * ldw + n0 + n];
            }
        }
        __syncthreads();
#pragma unroll
        for (int k = 0; k < 16; ++k) {
            float a[4], b[4];
#pragma unroll
            for (int i = 0; i < 4; ++i) a[i] = As[k][tr * 4 + i];
#pragma unroll
            for (int j = 0; j < 4; ++j) b[j] = Bs[k][tc * 4 + j];
#pragma unroll
            for (int i = 0; i < 4; ++i)
#pragma unroll
                for (int j = 0; j < 4; ++j)
                    acc[i][j] += a[i] * b[j];
        }
        __syncthreads();
    }

    // ---- epilogue: bias + act, float4 stores
    const float4 bv = *reinterpret_cast<const float4*>(&bias[n0 + tc * 4]);
#pragma unroll
    for (int i = 0; i < 4; ++i) {
        const int gm = m0 + tr * 4 + i;
        if (gm >= M) continue;
        float4 r;
        r.x = acc[i][0] + bv.x;
        r.y = acc[i][1] + bv.y;
        r.z = acc[i][2] + bv.z;
        r.w = acc[i][3] + bv.w;
        if (RELU) {
            r.x = fmaxf(r.x, 0.f); r.y = fmaxf(r.y, 0.f);
            r.z = fmaxf(r.z, 0.f); r.w = fmaxf(r.w, 0.f);
        }
        *reinterpret_cast<float4*>(&C[(size_t)gm * ldc + n0 + tc * 4]) = r;
    }
}

// ---------------------------------------------------------------------------
// Edge kernel: one wave per edge, lane handles channels {lane, lane+64}.
// kqvs row layout per node: [k(128) | q(128) | v(128) | s(128)] stride 512.
// e = edge_attr @ We computed in-register (edge_attr reads are wave-uniform
// scalar loads). msg scatter-added into agg via fp32 atomics.
// ---------------------------------------------------------------------------
__global__ __launch_bounds__(256)
void edge_kernel(const int* __restrict__ ei,        // [2][E]
                 const float* __restrict__ ea,      // [E][21]
                 const float* __restrict__ We,      // [21][128]
                 const float* __restrict__ kqvs,    // [N][512]
                 float* __restrict__ agg,           // [N][128]
                 int E)
{
    const int gid  = blockIdx.x * blockDim.x + threadIdx.x;
    const int e    = __builtin_amdgcn_readfirstlane(gid >> 6);
    const int lane = threadIdx.x & 63;
    if (e >= E) return;

    const int s = ei[e];        // src
    const int d = ei[NE + e];   // dst

    float e0 = 0.f, e1 = 0.f;
#pragma unroll
    for (int q = 0; q < 21; ++q) {
        const float a = ea[(size_t)e * 21 + q];   // uniform -> s_load
        e0 += a * We[q * HH + lane];
        e1 += a * We[q * HH + 64 + lane];
    }

    const float* rd = kqvs + (size_t)d * 512;
    const float* rs = kqvs + (size_t)s * 512;

    float g0 = rd[lane]      + rs[128 + lane] + 2.f * e0;
    float g1 = rd[64 + lane] + rs[192 + lane] + 2.f * e1;
    g0 = 1.f / (1.f + __expf(-g0));
    g1 = 1.f / (1.f + __expf(-g1));

    const float m0 = g0 * (rs[256 + lane] + e0);
    const float m1 = g1 * (rs[320 + lane] + e1);

    atomicAdd(&agg[(size_t)d * HH + lane],      m0);
    atomicAdd(&agg[(size_t)d * HH + 64 + lane], m1);
}

// ---------------------------------------------------------------------------
// Node update after conv: out = relu(agg + s)   (s = kqvs[:, 384:512])
// ---------------------------------------------------------------------------
__global__ __launch_bounds__(256)
void update_kernel(const float* __restrict__ agg,
                   const float* __restrict__ kqvs,
                   float* __restrict__ out, int M)
{
    const int idx = blockIdx.x * blockDim.x + threadIdx.x;   // over M*32 float4s
    if (idx >= M * 32) return;
    const int n  = idx >> 5;
    const int c4 = (idx & 31) << 2;
    const float4 a = *reinterpret_cast<const float4*>(&agg[(size_t)n * HH + c4]);
    const float4 s = *reinterpret_cast<const float4*>(&kqvs[(size_t)n * 512 + 384 + c4]);
    float4 r;
    r.x = fmaxf(a.x + s.x, 0.f);
    r.y = fmaxf(a.y + s.y, 0.f);
    r.z = fmaxf(a.z + s.z, 0.f);
    r.w = fmaxf(a.w + s.w, 0.f);
    *reinterpret_cast<float4*>(&out[(size_t)n * HH + c4]) = r;
}

// ---------------------------------------------------------------------------
// Column sum of g2 [M][128] -> gsum[128] (atomic partials, zeroed beforehand)
// ---------------------------------------------------------------------------
__global__ __launch_bounds__(128)
void colsum_kernel(const float* __restrict__ g2, float* __restrict__ gsum, int M)
{
    const int c     = threadIdx.x;                    // 0..127
    const int nb    = gridDim.x;
    const int chunk = (M + nb - 1) / nb;
    const int r0    = blockIdx.x * chunk;
    const int r1    = min(M, r0 + chunk);
    float acc = 0.f;
    for (int r = r0; r < r1; ++r) acc += g2[(size_t)r * HH + c];
    atomicAdd(&gsum[c], acc);
}

// ---------------------------------------------------------------------------
// gvec[256] = bl1 + (gsum/M) @ Wl1[128:256, :]
// ---------------------------------------------------------------------------
__global__ __launch_bounds__(256)
void gvec_kernel(const float* __restrict__ gsum,
                 const float* __restrict__ Wl1,
                 const float* __restrict__ bl1,
                 float* __restrict__ gvec, float invM)
{
    const int j = threadIdx.x;   // 0..255
    float acc = bl1[j];
    for (int k = 0; k < 128; ++k)
        acc += (gsum[k] * invM) * Wl1[(size_t)(128 + k) * 256 + j];
    gvec[j] = acc;
}

// ---------------------------------------------------------------------------
// Head out: out[n] = dot(u2[n][0:128], Wl3) + bl3.  Block = 64 rows.
// 4 lanes per row, 32 elems each, shfl-reduce.
// ---------------------------------------------------------------------------
__global__ __launch_bounds__(256)
void head_out_kernel(const float* __restrict__ u2,
                     const float* __restrict__ Wl3,
                     const float* __restrict__ bl3,
                     float* __restrict__ out, int M)
{
    __shared__ float w[128];
    const int t = threadIdx.x;
    if (t < 128) w[t] = Wl3[t];
    __syncthreads();

    const int lane = t & 63;
    const int wv   = t >> 6;
    const int r    = blockIdx.x * 64 + wv * 16 + (lane >> 2);
    const int p    = lane & 3;
    float acc = 0.f;
    if (r < M) {
        const float* row = u2 + (size_t)r * HH + p * 32;
#pragma unroll
        for (int j = 0; j < 32; ++j) acc += row[j] * w[p * 32 + j];
    }
    acc += __shfl_xor(acc, 1);
    acc += __shfl_xor(acc, 2);
    if (p == 0 && r < M) out[r] = acc + bl3[0];
}

// ---------------------------------------------------------------------------
extern "C" void kernel_launch(void* const* d_in, const int* in_sizes, int n_in,
                              void* d_out, int out_size, void* d_ws, size_t ws_size,
                              hipStream_t stream)
{
    const float* G   = (const float*)d_in[0];
    const int*   ei  = (const int*)  d_in[1];
    const float* ea  = (const float*)d_in[2];
    const float* We1 = (const float*)d_in[3];  const float* be1 = (const float*)d_in[4];
    const float* We2 = (const float*)d_in[5];  const float* be2 = (const float*)d_in[6];
    const float* We3 = (const float*)d_in[7];  const float* be3 = (const float*)d_in[8];
    const float* c1_Wk = (const float*)d_in[9];  const float* c1_bk = (const float*)d_in[10];
    const float* c1_Wq = (const float*)d_in[11]; const float* c1_bq = (const float*)d_in[12];
    const float* c1_Wv = (const float*)d_in[13]; const float* c1_bv = (const float*)d_in[14];
    const float* c1_We = (const float*)d_in[15];
    const float* c1_Ws = (const float*)d_in[16]; const float* c1_bs = (const float*)d_in[17];
    const float* c2_Wk = (const float*)d_in[18]; const float* c2_bk = (const float*)d_in[19];
    const float* c2_Wq = (const float*)d_in[20]; const float* c2_bq = (const float*)d_in[21];
    const float* c2_Wv = (const float*)d_in[22]; const float* c2_bv = (const float*)d_in[23];
    const float* c2_We = (const float*)d_in[24];
    const float* c2_Ws = (const float*)d_in[25]; const float* c2_bs = (const float*)d_in[26];
    const float* Wg1 = (const float*)d_in[27]; const float* bg1 = (const float*)d_in[28];
    const float* Wg2 = (const float*)d_in[29]; const float* bg2 = (const float*)d_in[30];
    const float* Wl1 = (const float*)d_in[31]; const float* bl1 = (const float*)d_in[32];
    const float* Wl2 = (const float*)d_in[33]; const float* bl2 = (const float*)d_in[34];
    const float* Wl3 = (const float*)d_in[35]; const float* bl3 = (const float*)d_in[36];

    float* out = (float*)d_out;

    // workspace layout (bytes)
    const size_t SZ_A = (size_t)NN * HH  * 4;   // 25.6 MB
    const size_t SZ_B = (size_t)NN * 512 * 4;   // 102.4 MB
    char* ws = (char*)d_ws;
    float* bufA = (float*)(ws);                         // [N][128]
    float* bufC = (float*)(ws + SZ_A);                  // [N][128] (agg / h / u2)
    float* bufB = (float*)(ws + 2 * SZ_A);              // [N][512] (kqvs / u1)
    float* gsum = (float*)(ws + 2 * SZ_A + SZ_B);       // [128]
    float* gvec = gsum + 128;                           // [256]

    const dim3 blk(256);
    const int  MB = (NN + 63) / 64;                     // 782 row blocks
    const dim3 g128(2, MB), g256(4, MB);

    // ---- node-feature MLP
    gemm_kernel<true><<<dim3(2, MB), blk, 0, stream>>>(G,    64,  We1, 128, be1, bufA, 128, NN, 64);
    gemm_kernel<true><<<dim3(2, MB), blk, 0, stream>>>(bufA, 128, We2, 128, be2, bufC, 128, NN, 128);
    gemm_kernel<true><<<dim3(2, MB), blk, 0, stream>>>(bufC, 128, We3, 128, be3, bufA, 128, NN, 128);

    // ---- conv1: kqvs GEMMs into bufB, edge scatter into bufC, update -> bufA
    gemm_kernel<false><<<g128, blk, 0, stream>>>(bufA, 128, c1_Wk, 128, c1_bk, bufB + 0,   512, NN, 128);
    gemm_kernel<false><<<g128, blk, 0, stream>>>(bufA, 128, c1_Wq, 128, c1_bq, bufB + 128, 512, NN, 128);
    gemm_kernel<false><<<g128, blk, 0, stream>>>(bufA, 128, c1_Wv, 128, c1_bv, bufB + 256, 512, NN, 128);
    gemm_kernel<false><<<g128, blk, 0, stream>>>(bufA, 128, c1_Ws, 128, c1_bs, bufB + 384, 512, NN, 128);
    hipMemsetAsync(bufC, 0, SZ_A, stream);
    edge_kernel<<<dim3(NE / 4), blk, 0, stream>>>(ei, ea, c1_We, bufB, bufC, NE);
    update_kernel<<<dim3((NN * 32 + 255) / 256), blk, 0, stream>>>(bufC, bufB, bufA, NN);

    // ---- conv2
    gemm_kernel<false><<<g128, blk, 0, stream>>>(bufA, 128, c2_Wk, 128, c2_bk, bufB + 0,   512, NN, 128);
    gemm_kernel<false><<<g128, blk, 0, stream>>>(bufA, 128, c2_Wq, 128, c2_bq, bufB + 128, 512, NN, 128);
    gemm_kernel<false><<<g128, blk, 0, stream>>>(bufA, 128, c2_Wv, 128, c2_bv, bufB + 256, 512, NN, 128);
    gemm_kernel<false><<<g128, blk, 0, stream>>>(bufA, 128, c2_Ws, 128, c2_bs, bufB + 384, 512, NN, 128);
    hipMemsetAsync(bufC, 0, SZ_A, stream);
    edge_kernel<<<dim3(NE / 4), blk, 0, stream>>>(ei, ea, c2_We, bufB, bufC, NE);
    update_kernel<<<dim3((NN * 32 + 255) / 256), blk, 0, stream>>>(bufC, bufB, bufA, NN);

    // ---- graph-level MLP
    gemm_kernel<true ><<<g128, blk, 0, stream>>>(bufA, 128, Wg1, 128, bg1, bufC, 128, NN, 128);
    gemm_kernel<false><<<g128, blk, 0, stream>>>(bufC, 128, Wg2, 128, bg2, bufA, 128, NN, 128);  // g2

    // ---- graph mean -> gvec (bias for head GEMM)
    hipMemsetAsync(gsum, 0, 128 * 4, stream);
    colsum_kernel<<<dim3(256), dim3(128), 0, stream>>>(bufA, gsum, NN);
    gvec_kernel<<<dim3(1), dim3(256), 0, stream>>>(gsum, Wl1, bl1, gvec, 1.f / NN);

    // ---- head
    gemm_kernel<true><<<g256, blk, 0, stream>>>(bufA, 128, Wl1, 256, gvec, bufB, 256, NN, 128);  // u1
    gemm_kernel<true><<<g128, blk, 0, stream>>>(bufB, 256, Wl2, 128, bl2, bufC, 128, NN, 256);   // u2
    head_out_kernel<<<dim3(MB), blk, 0, stream>>>(bufC, Wl3, bl3, out, NN);
}

// Round 2
// 974.151 us; speedup vs baseline: 1.3425x; 1.3425x over previous
//
#include <hip/hip_runtime.h>

#define NN 50000
#define NE 800000
#define HH 128
#define SCAN_BS 512
#define SCAN_NB ((NN + SCAN_BS - 1) / SCAN_BS)   // 98

// ---------------------------------------------------------------------------
// Tiled fp32 GEMM: C[m][n] = act(bias[n] + sum_k A[m][k]*W[k][n])
// Tile 64x64, BK=16, 256 threads, 4x4 micro-tile per thread.
// ---------------------------------------------------------------------------
template<bool RELU>
__global__ __launch_bounds__(256)
void gemm_kernel(const float* __restrict__ A, int lda,
                 const float* __restrict__ W, int ldw,
                 const float* __restrict__ bias,
                 float* __restrict__ C, int ldc,
                 int M, int K)
{
    __shared__ float As[16][68];
    __shared__ float Bs[16][64];

    const int t  = threadIdx.x;
    const int m0 = blockIdx.y << 6;
    const int n0 = blockIdx.x << 6;
    const int tr = t >> 4;
    const int tc = t & 15;

    float acc[4][4] = {};

    for (int k0 = 0; k0 < K; k0 += 16) {
        {
            const int k  = t & 15;
            const int mb = t >> 4;
#pragma unroll
            for (int i = 0; i < 4; ++i) {
                const int m  = mb + (i << 4);
                const int gm = m0 + m;
                float v = 0.f;
                if (gm < M) v = A[(size_t)gm * lda + k0 + k];
                As[k][m] = v;
            }
        }
        {
            const int n  = t & 63;
            const int kb = t >> 6;
#pragma unroll
            for (int i = 0; i < 4; ++i) {
                const int k2 = kb + (i << 2);
                Bs[k2][n] = W[(size_t)(k0 + k2) * ldw + n0 + n];
            }
        }
        __syncthreads();
#pragma unroll
        for (int k = 0; k < 16; ++k) {
            float a[4], b[4];
#pragma unroll
            for (int i = 0; i < 4; ++i) a[i] = As[k][tr * 4 + i];
#pragma unroll
            for (int j = 0; j < 4; ++j) b[j] = Bs[k][tc * 4 + j];
#pragma unroll
            for (int i = 0; i < 4; ++i)
#pragma unroll
                for (int j = 0; j < 4; ++j)
                    acc[i][j] += a[i] * b[j];
        }
        __syncthreads();
    }

    const float4 bv = *reinterpret_cast<const float4*>(&bias[n0 + tc * 4]);
#pragma unroll
    for (int i = 0; i < 4; ++i) {
        const int gm = m0 + tr * 4 + i;
        if (gm >= M) continue;
        float4 r;
        r.x = acc[i][0] + bv.x;
        r.y = acc[i][1] + bv.y;
        r.z = acc[i][2] + bv.z;
        r.w = acc[i][3] + bv.w;
        if (RELU) {
            r.x = fmaxf(r.x, 0.f); r.y = fmaxf(r.y, 0.f);
            r.z = fmaxf(r.z, 0.f); r.w = fmaxf(r.w, 0.f);
        }
        *reinterpret_cast<float4*>(&C[(size_t)gm * ldc + n0 + tc * 4]) = r;
    }
}

// ---------------------------------------------------------------------------
// CSR build: histogram -> scan -> scatter (runs once per call, both convs use it)
// ---------------------------------------------------------------------------
__global__ __launch_bounds__(256)
void hist_kernel(const int* __restrict__ ei, int* __restrict__ deg)
{
    const int e = blockIdx.x * 256 + threadIdx.x;
    if (e < NE) atomicAdd(&deg[ei[NE + e]], 1);
}

__global__ __launch_bounds__(SCAN_BS)
void scan1_kernel(const int* __restrict__ deg, int* __restrict__ incl,
                  int* __restrict__ bsum)
{
    __shared__ int sm[SCAN_BS];
    const int t = threadIdx.x;
    const int i = blockIdx.x * SCAN_BS + t;
    sm[t] = (i < NN) ? deg[i] : 0;
    __syncthreads();
    for (int d = 1; d < SCAN_BS; d <<= 1) {
        const int add = (t >= d) ? sm[t - d] : 0;
        __syncthreads();
        sm[t] += add;
        __syncthreads();
    }
    if (i < NN) incl[i] = sm[t];
    if (t == SCAN_BS - 1) bsum[blockIdx.x] = sm[t];
}

__global__ void scan2_kernel(int* __restrict__ bsum)
{
    if (threadIdx.x == 0 && blockIdx.x == 0) {
        int run = 0;
        for (int i = 0; i < SCAN_NB; ++i) { const int v = bsum[i]; bsum[i] = run; run += v; }
    }
}

__global__ __launch_bounds__(SCAN_BS)
void scan3_kernel(const int* __restrict__ incl, const int* __restrict__ deg,
                  const int* __restrict__ bsum, int* __restrict__ offs)
{
    const int t = threadIdx.x;
    const int i = blockIdx.x * SCAN_BS + t;
    if (i < NN) offs[i] = incl[i] - deg[i] + bsum[blockIdx.x];
    if (i == 0) offs[NN] = NE;
}

__global__ __launch_bounds__(256)
void scatter_kernel(const int* __restrict__ ei, const int* __restrict__ offs,
                    int* __restrict__ cur, int2* __restrict__ csr)
{
    const int e = blockIdx.x * 256 + threadIdx.x;
    if (e >= NE) return;
    const int d = ei[NE + e];
    const int p = offs[d] + atomicAdd(&cur[d], 1);
    csr[p] = make_int2(ei[e], e);
}

// ---------------------------------------------------------------------------
// Fused conv aggregation + skip + ReLU. One wave per dst node; lane handles
// channels {lane, lane+64}. kqvs row layout: [k(0:128)|s(128:256)|q(256:384)|v(384:512)].
// No atomics: per-node register accumulation, single coalesced write.
// ---------------------------------------------------------------------------
__global__ __launch_bounds__(256)
void conv_agg_kernel(const int* __restrict__ offs,     // [N+1]
                     const int2* __restrict__ csr,     // [E] (src, edge_id)
                     const float* __restrict__ ea,     // [E][21]
                     const float* __restrict__ We,     // [21][128]
                     const float* __restrict__ kqvs,   // [N][512]
                     float* __restrict__ out)          // [N][128]
{
    __shared__ float we[21 * 128];
    const int t = threadIdx.x;
    for (int i = t; i < 21 * 128; i += 256) we[i] = We[i];
    __syncthreads();

    const int lane = t & 63;
    const int n = blockIdx.x * 4 + (t >> 6);
    if (n >= NN) return;

    const float* row = kqvs + (size_t)n * 512;
    const float kd0 = row[lane];
    const float kd1 = row[64 + lane];

    const int j0 = offs[n], j1 = offs[n + 1];
    float acc0 = 0.f, acc1 = 0.f;
    for (int j = j0; j < j1; ++j) {
        const int2 se   = csr[j];
        const int  s    = __builtin_amdgcn_readfirstlane(se.x);
        const int  eidx = __builtin_amdgcn_readfirstlane(se.y);

        const float* av = ea + (size_t)eidx * 21;
        float e0 = 0.f, e1 = 0.f;
#pragma unroll
        for (int q = 0; q < 21; ++q) {
            const float a = av[q];                 // wave-uniform scalar load
            e0 += a * we[q * HH + lane];
            e1 += a * we[q * HH + 64 + lane];
        }

        const float* rs = kqvs + (size_t)s * 512 + 256;   // q|v of src
        const float qs0 = rs[lane],       qs1 = rs[64 + lane];
        const float vs0 = rs[128 + lane], vs1 = rs[192 + lane];

        float g0 = kd0 + qs0 + 2.f * e0;
        float g1 = kd1 + qs1 + 2.f * e1;
        g0 = 1.f / (1.f + __expf(-g0));
        g1 = 1.f / (1.f + __expf(-g1));

        acc0 += g0 * (vs0 + e0);
        acc1 += g1 * (vs1 + e1);
    }

    const float s0 = row[128 + lane], s1 = row[192 + lane];
    out[(size_t)n * HH + lane]      = fmaxf(acc0 + s0, 0.f);
    out[(size_t)n * HH + 64 + lane] = fmaxf(acc1 + s1, 0.f);
}

// ---------------------------------------------------------------------------
__global__ __launch_bounds__(128)
void colsum_kernel(const float* __restrict__ g2, float* __restrict__ gsum, int M)
{
    const int c     = threadIdx.x;
    const int nb    = gridDim.x;
    const int chunk = (M + nb - 1) / nb;
    const int r0    = blockIdx.x * chunk;
    const int r1    = min(M, r0 + chunk);
    float acc = 0.f;
    for (int r = r0; r < r1; ++r) acc += g2[(size_t)r * HH + c];
    atomicAdd(&gsum[c], acc);
}

__global__ __launch_bounds__(256)
void gvec_kernel(const float* __restrict__ gsum,
                 const float* __restrict__ Wl1,
                 const float* __restrict__ bl1,
                 float* __restrict__ gvec, float invM)
{
    const int j = threadIdx.x;
    float acc = bl1[j];
    for (int k = 0; k < 128; ++k)
        acc += (gsum[k] * invM) * Wl1[(size_t)(128 + k) * 256 + j];
    gvec[j] = acc;
}

__global__ __launch_bounds__(256)
void head_out_kernel(const float* __restrict__ u2,
                     const float* __restrict__ Wl3,
                     const float* __restrict__ bl3,
                     float* __restrict__ out, int M)
{
    __shared__ float w[128];
    const int t = threadIdx.x;
    if (t < 128) w[t] = Wl3[t];
    __syncthreads();

    const int lane = t & 63;
    const int wv   = t >> 6;
    const int r    = blockIdx.x * 64 + wv * 16 + (lane >> 2);
    const int p    = lane & 3;
    float acc = 0.f;
    if (r < M) {
        const float* row = u2 + (size_t)r * HH + p * 32;
#pragma unroll
        for (int j = 0; j < 32; ++j) acc += row[j] * w[p * 32 + j];
    }
    acc += __shfl_xor(acc, 1);
    acc += __shfl_xor(acc, 2);
    if (p == 0 && r < M) out[r] = acc + bl3[0];
}

// ---------------------------------------------------------------------------
extern "C" void kernel_launch(void* const* d_in, const int* in_sizes, int n_in,
                              void* d_out, int out_size, void* d_ws, size_t ws_size,
                              hipStream_t stream)
{
    const float* G   = (const float*)d_in[0];
    const int*   ei  = (const int*)  d_in[1];
    const float* ea  = (const float*)d_in[2];
    const float* We1 = (const float*)d_in[3];  const float* be1 = (const float*)d_in[4];
    const float* We2 = (const float*)d_in[5];  const float* be2 = (const float*)d_in[6];
    const float* We3 = (const float*)d_in[7];  const float* be3 = (const float*)d_in[8];
    const float* c1_Wk = (const float*)d_in[9];  const float* c1_bk = (const float*)d_in[10];
    const float* c1_Wq = (const float*)d_in[11]; const float* c1_bq = (const float*)d_in[12];
    const float* c1_Wv = (const float*)d_in[13]; const float* c1_bv = (const float*)d_in[14];
    const float* c1_We = (const float*)d_in[15];
    const float* c1_Ws = (const float*)d_in[16]; const float* c1_bs = (const float*)d_in[17];
    const float* c2_Wk = (const float*)d_in[18]; const float* c2_bk = (const float*)d_in[19];
    const float* c2_Wq = (const float*)d_in[20]; const float* c2_bq = (const float*)d_in[21];
    const float* c2_Wv = (const float*)d_in[22]; const float* c2_bv = (const float*)d_in[23];
    const float* c2_We = (const float*)d_in[24];
    const float* c2_Ws = (const float*)d_in[25]; const float* c2_bs = (const float*)d_in[26];
    const float* Wg1 = (const float*)d_in[27]; const float* bg1 = (const float*)d_in[28];
    const float* Wg2 = (const float*)d_in[29]; const float* bg2 = (const float*)d_in[30];
    const float* Wl1 = (const float*)d_in[31]; const float* bl1 = (const float*)d_in[32];
    const float* Wl2 = (const float*)d_in[33]; const float* bl2 = (const float*)d_in[34];
    const float* Wl3 = (const float*)d_in[35]; const float* bl3 = (const float*)d_in[36];

    float* out = (float*)d_out;

    // ---- workspace layout (bytes)
    const size_t SZ_A = (size_t)NN * HH  * 4;   // 25.6 MB
    const size_t SZ_B = (size_t)NN * 512 * 4;   // 102.4 MB
    char* ws = (char*)d_ws;
    size_t off = 0;
    float* bufA = (float*)(ws + off); off += SZ_A;
    float* bufC = (float*)(ws + off); off += SZ_A;
    float* bufB = (float*)(ws + off); off += SZ_B;
    float* gsum = (float*)(ws + off); off += 256 * 4;
    float* gvec = (float*)(ws + off); off += 256 * 4;
    int*   deg  = (int*)  (ws + off); off += (size_t)NN * 4;
    int*   incl = (int*)  (ws + off); off += (size_t)NN * 4;
    int*   bsum = (int*)  (ws + off); off += 128 * 4;
    int*   offs = (int*)  (ws + off); off += (size_t)(NN + 2) * 4;
    int*   cur  = (int*)  (ws + off); off += (size_t)NN * 4;
    off = (off + 15) & ~(size_t)15;
    int2*  csr  = (int2*) (ws + off); off += (size_t)NE * 8;

    const dim3 blk(256);
    const int  MB = (NN + 63) / 64;
    const dim3 g128(2, MB), g256(4, MB);
    const int  EB = (NE + 255) / 256;
    const int  AGGB = (NN + 3) / 4;

    // ---- CSR build (shared by both convs)
    hipMemsetAsync(deg, 0, (size_t)NN * 4, stream);
    hipMemsetAsync(cur, 0, (size_t)NN * 4, stream);
    hist_kernel<<<dim3(EB), blk, 0, stream>>>(ei, deg);
    scan1_kernel<<<dim3(SCAN_NB), dim3(SCAN_BS), 0, stream>>>(deg, incl, bsum);
    scan2_kernel<<<dim3(1), dim3(64), 0, stream>>>(bsum);
    scan3_kernel<<<dim3(SCAN_NB), dim3(SCAN_BS), 0, stream>>>(incl, deg, bsum, offs);
    scatter_kernel<<<dim3(EB), blk, 0, stream>>>(ei, offs, cur, csr);

    // ---- node-feature MLP
    gemm_kernel<true><<<g128, blk, 0, stream>>>(G,    64,  We1, 128, be1, bufA, 128, NN, 64);
    gemm_kernel<true><<<g128, blk, 0, stream>>>(bufA, 128, We2, 128, be2, bufC, 128, NN, 128);
    gemm_kernel<true><<<g128, blk, 0, stream>>>(bufC, 128, We3, 128, be3, bufA, 128, NN, 128);

    // ---- conv1: kqvs layout [k|s|q|v]
    gemm_kernel<false><<<g128, blk, 0, stream>>>(bufA, 128, c1_Wk, 128, c1_bk, bufB + 0,   512, NN, 128);
    gemm_kernel<false><<<g128, blk, 0, stream>>>(bufA, 128, c1_Ws, 128, c1_bs, bufB + 128, 512, NN, 128);
    gemm_kernel<false><<<g128, blk, 0, stream>>>(bufA, 128, c1_Wq, 128, c1_bq, bufB + 256, 512, NN, 128);
    gemm_kernel<false><<<g128, blk, 0, stream>>>(bufA, 128, c1_Wv, 128, c1_bv, bufB + 384, 512, NN, 128);
    conv_agg_kernel<<<dim3(AGGB), blk, 0, stream>>>(offs, csr, ea, c1_We, bufB, bufA);

    // ---- conv2
    gemm_kernel<false><<<g128, blk, 0, stream>>>(bufA, 128, c2_Wk, 128, c2_bk, bufB + 0,   512, NN, 128);
    gemm_kernel<false><<<g128, blk, 0, stream>>>(bufA, 128, c2_Ws, 128, c2_bs, bufB + 128, 512, NN, 128);
    gemm_kernel<false><<<g128, blk, 0, stream>>>(bufA, 128, c2_Wq, 128, c2_bq, bufB + 256, 512, NN, 128);
    gemm_kernel<false><<<g128, blk, 0, stream>>>(bufA, 128, c2_Wv, 128, c2_bv, bufB + 384, 512, NN, 128);
    conv_agg_kernel<<<dim3(AGGB), blk, 0, stream>>>(offs, csr, ea, c2_We, bufB, bufA);

    // ---- graph-level MLP
    gemm_kernel<true ><<<g128, blk, 0, stream>>>(bufA, 128, Wg1, 128, bg1, bufC, 128, NN, 128);
    gemm_kernel<false><<<g128, blk, 0, stream>>>(bufC, 128, Wg2, 128, bg2, bufA, 128, NN, 128);  // g2

    // ---- graph mean -> gvec
    hipMemsetAsync(gsum, 0, 128 * 4, stream);
    colsum_kernel<<<dim3(256), dim3(128), 0, stream>>>(bufA, gsum, NN);
    gvec_kernel<<<dim3(1), dim3(256), 0, stream>>>(gsum, Wl1, bl1, gvec, 1.f / NN);

    // ---- head
    gemm_kernel<true><<<g256, blk, 0, stream>>>(bufA, 128, Wl1, 256, gvec, bufB, 256, NN, 128);  // u1
    gemm_kernel<true><<<g128, blk, 0, stream>>>(bufB, 256, Wl2, 128, bl2, bufC, 128, NN, 256);   // u2
    head_out_kernel<<<dim3(MB), blk, 0, stream>>>(bufC, Wl3, bl3, out, NN);
}

// Round 3
// 802.924 us; speedup vs baseline: 1.6287x; 1.2133x over previous
//
#include <hip/hip_runtime.h>

#define NN 50000
#define NE 800000
#define HH 128
#define SCAN_BS 512
#define SCAN_NB ((NN + SCAN_BS - 1) / SCAN_BS)   // 98

typedef short bf16x8 __attribute__((ext_vector_type(8)));
typedef short bf16x4 __attribute__((ext_vector_type(4)));
typedef float f32x4  __attribute__((ext_vector_type(4)));

// ---------------------------------------------------------------------------
// fp32 -> bf16 hi/lo split (RNE)
// ---------------------------------------------------------------------------
__device__ __forceinline__ void split_bf16(float x, short& h, short& l)
{
    unsigned u = __builtin_bit_cast(unsigned, x);
    unsigned r = u + 0x7FFFu + ((u >> 16) & 1u);
    h = (short)(r >> 16);
    float hf = __builtin_bit_cast(float, (unsigned)((r >> 16) << 16));
    float lf = x - hf;
    unsigned u2 = __builtin_bit_cast(unsigned, lf);
    unsigned r2 = u2 + 0x7FFFu + ((u2 >> 16) & 1u);
    l = (short)(r2 >> 16);
}

// ---------------------------------------------------------------------------
// Split-bf16 MFMA GEMM: C = act(bias + A@W), fp32 in/out, fp32-grade accuracy.
// Block tile 128x128, BK=32, 256 threads = 4 waves (2x2), 64x64 per wave.
// LDS: [row][k] bf16, row stride 40 shorts (80B, 16B-aligned, padded).
// ---------------------------------------------------------------------------
#define LDK 40

template<bool RELU>
__global__ __launch_bounds__(256)
void gemm_mfma(const float* __restrict__ A, int lda,
               const float* __restrict__ W, int ldw,
               const float* __restrict__ bias,
               float* __restrict__ C, int ldc,
               int M, int K)
{
    __shared__ short Ah[128 * LDK], Al[128 * LDK];
    __shared__ short Bh[128 * LDK], Bl[128 * LDK];

    const int t    = threadIdx.x;
    const int m0   = blockIdx.y << 7;
    const int n0   = blockIdx.x << 7;
    const int lane = t & 63;
    const int wid  = t >> 6;
    const int wr   = wid >> 1, wc = wid & 1;   // wave tile origin (wr*64, wc*64)
    const int fr   = lane & 15;                // fragment row/col
    const int fg   = lane >> 4;                // k-group (0..3)

    f32x4 acc[4][4] = {};                      // [mi][nj]

    for (int k0 = 0; k0 < K; k0 += 32) {
        // ---- stage A: 128 rows x 32 k, fp32 -> hi/lo bf16
        {
            const int m  = t >> 1;
            const int kh = (t & 1) << 4;       // 0 or 16
            const int gm = m0 + m;
            float f[16];
            if (gm < M) {
                const float* p = A + (size_t)gm * lda + k0 + kh;
#pragma unroll
                for (int x = 0; x < 4; ++x) {
                    const float4 v = *reinterpret_cast<const float4*>(p + x * 4);
                    f[x * 4 + 0] = v.x; f[x * 4 + 1] = v.y;
                    f[x * 4 + 2] = v.z; f[x * 4 + 3] = v.w;
                }
            } else {
#pragma unroll
                for (int x = 0; x < 16; ++x) f[x] = 0.f;
            }
            bf16x8 h0, h1, l0, l1;
#pragma unroll
            for (int x = 0; x < 8; ++x) { short h, l; split_bf16(f[x],     h, l); h0[x] = h; l0[x] = l; }
#pragma unroll
            for (int x = 0; x < 8; ++x) { short h, l; split_bf16(f[8 + x], h, l); h1[x] = h; l1[x] = l; }
            *reinterpret_cast<bf16x8*>(&Ah[m * LDK + kh])     = h0;
            *reinterpret_cast<bf16x8*>(&Ah[m * LDK + kh + 8]) = h1;
            *reinterpret_cast<bf16x8*>(&Al[m * LDK + kh])     = l0;
            *reinterpret_cast<bf16x8*>(&Al[m * LDK + kh + 8]) = l1;
        }
        // ---- stage B transposed: Bs[n][k], from W[k][n]
        {
            const int n  = t & 127;
            const int kb = (t >> 7) << 2;      // 0 or 4
#pragma unroll
            for (int kk0 = 0; kk0 < 32; kk0 += 8) {
                const int kk = kk0 + kb;
                bf16x4 hv, lv;
#pragma unroll
                for (int x = 0; x < 4; ++x) {
                    const float v = W[(size_t)(k0 + kk + x) * ldw + n0 + n];
                    short h, l; split_bf16(v, h, l);
                    hv[x] = h; lv[x] = l;
                }
                *reinterpret_cast<bf16x4*>(&Bh[n * LDK + kk]) = hv;
                *reinterpret_cast<bf16x4*>(&Bl[n * LDK + kk]) = lv;
            }
        }
        __syncthreads();

        // ---- fragments + 3-term MFMA
        bf16x8 ah[4], al[4], bh[4], bl[4];
#pragma unroll
        for (int i = 0; i < 4; ++i) {
            const int m = wr * 64 + i * 16 + fr;
            ah[i] = *reinterpret_cast<const bf16x8*>(&Ah[m * LDK + fg * 8]);
            al[i] = *reinterpret_cast<const bf16x8*>(&Al[m * LDK + fg * 8]);
        }
#pragma unroll
        for (int j = 0; j < 4; ++j) {
            const int n = wc * 64 + j * 16 + fr;
            bh[j] = *reinterpret_cast<const bf16x8*>(&Bh[n * LDK + fg * 8]);
            bl[j] = *reinterpret_cast<const bf16x8*>(&Bl[n * LDK + fg * 8]);
        }
#pragma unroll
        for (int i = 0; i < 4; ++i)
#pragma unroll
            for (int j = 0; j < 4; ++j) {
                f32x4 a = acc[i][j];
                a = __builtin_amdgcn_mfma_f32_16x16x32_bf16(ah[i], bh[j], a, 0, 0, 0);
                a = __builtin_amdgcn_mfma_f32_16x16x32_bf16(ah[i], bl[j], a, 0, 0, 0);
                a = __builtin_amdgcn_mfma_f32_16x16x32_bf16(al[i], bh[j], a, 0, 0, 0);
                acc[i][j] = a;
            }
        __syncthreads();
    }

    // ---- epilogue: D row = fg*4 + r, col = fr (verified C/D layout)
#pragma unroll
    for (int j = 0; j < 4; ++j) {
        const int gn = n0 + wc * 64 + j * 16 + fr;
        const float bv = bias[gn];
#pragma unroll
        for (int i = 0; i < 4; ++i) {
            const int mbase = m0 + wr * 64 + i * 16 + fg * 4;
#pragma unroll
            for (int r = 0; r < 4; ++r) {
                const int gm = mbase + r;
                if (gm < M) {
                    float v = acc[i][j][r] + bv;
                    if (RELU) v = fmaxf(v, 0.f);
                    C[(size_t)gm * ldc + gn] = v;
                }
            }
        }
    }
}

// ---------------------------------------------------------------------------
// CSR build
// ---------------------------------------------------------------------------
__global__ __launch_bounds__(256)
void hist_kernel(const int* __restrict__ ei, int* __restrict__ deg)
{
    const int e = blockIdx.x * 256 + threadIdx.x;
    if (e < NE) atomicAdd(&deg[ei[NE + e]], 1);
}

__global__ __launch_bounds__(SCAN_BS)
void scan1_kernel(const int* __restrict__ deg, int* __restrict__ incl,
                  int* __restrict__ bsum)
{
    __shared__ int sm[SCAN_BS];
    const int t = threadIdx.x;
    const int i = blockIdx.x * SCAN_BS + t;
    sm[t] = (i < NN) ? deg[i] : 0;
    __syncthreads();
    for (int d = 1; d < SCAN_BS; d <<= 1) {
        const int add = (t >= d) ? sm[t - d] : 0;
        __syncthreads();
        sm[t] += add;
        __syncthreads();
    }
    if (i < NN) incl[i] = sm[t];
    if (t == SCAN_BS - 1) bsum[blockIdx.x] = sm[t];
}

__global__ void scan2_kernel(int* __restrict__ bsum)
{
    if (threadIdx.x == 0 && blockIdx.x == 0) {
        int run = 0;
        for (int i = 0; i < SCAN_NB; ++i) { const int v = bsum[i]; bsum[i] = run; run += v; }
    }
}

__global__ __launch_bounds__(SCAN_BS)
void scan3_kernel(const int* __restrict__ incl, const int* __restrict__ deg,
                  const int* __restrict__ bsum, int* __restrict__ offs)
{
    const int t = threadIdx.x;
    const int i = blockIdx.x * SCAN_BS + t;
    if (i < NN) offs[i] = incl[i] - deg[i] + bsum[blockIdx.x];
    if (i == 0) offs[NN] = NE;
}

__global__ __launch_bounds__(256)
void scatter_kernel(const int* __restrict__ ei, const int* __restrict__ offs,
                    int* __restrict__ cur, int2* __restrict__ csr)
{
    const int e = blockIdx.x * 256 + threadIdx.x;
    if (e >= NE) return;
    const int d = ei[NE + e];
    const int p = offs[d] + atomicAdd(&cur[d], 1);
    csr[p] = make_int2(ei[e], e);
}

// ---------------------------------------------------------------------------
// Fused conv aggregation + skip + ReLU. One wave per dst node.
// We held in 42 VGPRs (no LDS in the loop). kqvs layout [k|s|q|v], stride 512.
// ---------------------------------------------------------------------------
__global__ __launch_bounds__(256)
void conv_agg_kernel(const int* __restrict__ offs,
                     const int2* __restrict__ csr,
                     const float* __restrict__ ea,
                     const float* __restrict__ We,
                     const float* __restrict__ kqvs,
                     float* __restrict__ out)
{
    const int t    = threadIdx.x;
    const int lane = t & 63;
    const int n    = blockIdx.x * 4 + (t >> 6);
    if (n >= NN) return;

    // We -> registers (per-lane constant columns), fully unrolled -> static idx
    float w0[21], w1[21];
#pragma unroll
    for (int q = 0; q < 21; ++q) {
        w0[q] = We[q * HH + lane];
        w1[q] = We[q * HH + 64 + lane];
    }

    const float* row = kqvs + (size_t)n * 512;
    const float kd0 = row[lane];
    const float kd1 = row[64 + lane];

    const int j0 = offs[n], j1 = offs[n + 1];
    float acc0 = 0.f, acc1 = 0.f;

    int2 se = (j0 < j1) ? csr[j0] : make_int2(0, 0);
    for (int j = j0; j < j1; ++j) {
        const int2 se_n = (j + 1 < j1) ? csr[j + 1] : se;

        const int s    = __builtin_amdgcn_readfirstlane(se.x);
        const int eidx = __builtin_amdgcn_readfirstlane(se.y);

        // issue the gathers first so they overlap the 21-FMA chain
        const float* rs = kqvs + (size_t)s * 512 + 256;   // q|v of src
        const float qs0 = rs[lane],       qs1 = rs[64 + lane];
        const float vs0 = rs[128 + lane], vs1 = rs[192 + lane];

        const float* av = ea + (size_t)eidx * 21;
        float e0 = 0.f, e1 = 0.f;
#pragma unroll
        for (int q = 0; q < 21; ++q) {
            const float a = av[q];                        // uniform -> s_load
            e0 += a * w0[q];
            e1 += a * w1[q];
        }

        float g0 = kd0 + qs0 + 2.f * e0;
        float g1 = kd1 + qs1 + 2.f * e1;
        g0 = 1.f / (1.f + __expf(-g0));
        g1 = 1.f / (1.f + __expf(-g1));

        acc0 += g0 * (vs0 + e0);
        acc1 += g1 * (vs1 + e1);
        se = se_n;
    }

    const float s0 = row[128 + lane], s1 = row[192 + lane];
    out[(size_t)n * HH + lane]      = fmaxf(acc0 + s0, 0.f);
    out[(size_t)n * HH + 64 + lane] = fmaxf(acc1 + s1, 0.f);
}

// ---------------------------------------------------------------------------
__global__ __launch_bounds__(128)
void colsum_kernel(const float* __restrict__ g2, float* __restrict__ gsum, int M)
{
    const int c     = threadIdx.x;
    const int nb    = gridDim.x;
    const int chunk = (M + nb - 1) / nb;
    const int r0    = blockIdx.x * chunk;
    const int r1    = min(M, r0 + chunk);
    float acc = 0.f;
    for (int r = r0; r < r1; ++r) acc += g2[(size_t)r * HH + c];
    atomicAdd(&gsum[c], acc);
}

__global__ __launch_bounds__(256)
void gvec_kernel(const float* __restrict__ gsum,
                 const float* __restrict__ Wl1,
                 const float* __restrict__ bl1,
                 float* __restrict__ gvec, float invM)
{
    const int j = threadIdx.x;
    float acc = bl1[j];
    for (int k = 0; k < 128; ++k)
        acc += (gsum[k] * invM) * Wl1[(size_t)(128 + k) * 256 + j];
    gvec[j] = acc;
}

__global__ __launch_bounds__(256)
void head_out_kernel(const float* __restrict__ u2,
                     const float* __restrict__ Wl3,
                     const float* __restrict__ bl3,
                     float* __restrict__ out, int M)
{
    __shared__ float w[128];
    const int t = threadIdx.x;
    if (t < 128) w[t] = Wl3[t];
    __syncthreads();

    const int lane = t & 63;
    const int wv   = t >> 6;
    const int r    = blockIdx.x * 64 + wv * 16 + (lane >> 2);
    const int p    = lane & 3;
    float acc = 0.f;
    if (r < M) {
        const float* row = u2 + (size_t)r * HH + p * 32;
#pragma unroll
        for (int j = 0; j < 32; ++j) acc += row[j] * w[p * 32 + j];
    }
    acc += __shfl_xor(acc, 1);
    acc += __shfl_xor(acc, 2);
    if (p == 0 && r < M) out[r] = acc + bl3[0];
}

// ---------------------------------------------------------------------------
extern "C" void kernel_launch(void* const* d_in, const int* in_sizes, int n_in,
                              void* d_out, int out_size, void* d_ws, size_t ws_size,
                              hipStream_t stream)
{
    const float* G   = (const float*)d_in[0];
    const int*   ei  = (const int*)  d_in[1];
    const float* ea  = (const float*)d_in[2];
    const float* We1 = (const float*)d_in[3];  const float* be1 = (const float*)d_in[4];
    const float* We2 = (const float*)d_in[5];  const float* be2 = (const float*)d_in[6];
    const float* We3 = (const float*)d_in[7];  const float* be3 = (const float*)d_in[8];
    const float* c1_Wk = (const float*)d_in[9];  const float* c1_bk = (const float*)d_in[10];
    const float* c1_Wq = (const float*)d_in[11]; const float* c1_bq = (const float*)d_in[12];
    const float* c1_Wv = (const float*)d_in[13]; const float* c1_bv = (const float*)d_in[14];
    const float* c1_We = (const float*)d_in[15];
    const float* c1_Ws = (const float*)d_in[16]; const float* c1_bs = (const float*)d_in[17];
    const float* c2_Wk = (const float*)d_in[18]; const float* c2_bk = (const float*)d_in[19];
    const float* c2_Wq = (const float*)d_in[20]; const float* c2_bq = (const float*)d_in[21];
    const float* c2_Wv = (const float*)d_in[22]; const float* c2_bv = (const float*)d_in[23];
    const float* c2_We = (const float*)d_in[24];
    const float* c2_Ws = (const float*)d_in[25]; const float* c2_bs = (const float*)d_in[26];
    const float* Wg1 = (const float*)d_in[27]; const float* bg1 = (const float*)d_in[28];
    const float* Wg2 = (const float*)d_in[29]; const float* bg2 = (const float*)d_in[30];
    const float* Wl1 = (const float*)d_in[31]; const float* bl1 = (const float*)d_in[32];
    const float* Wl2 = (const float*)d_in[33]; const float* bl2 = (const float*)d_in[34];
    const float* Wl3 = (const float*)d_in[35]; const float* bl3 = (const float*)d_in[36];

    float* out = (float*)d_out;

    // ---- workspace layout
    const size_t SZ_A = (size_t)NN * HH  * 4;   // 25.6 MB
    const size_t SZ_B = (size_t)NN * 512 * 4;   // 102.4 MB
    char* ws = (char*)d_ws;
    size_t off = 0;
    float* bufA = (float*)(ws + off); off += SZ_A;
    float* bufC = (float*)(ws + off); off += SZ_A;
    float* bufB = (float*)(ws + off); off += SZ_B;
    float* gsum = (float*)(ws + off); off += 256 * 4;
    float* gvec = (float*)(ws + off); off += 256 * 4;
    int*   deg  = (int*)  (ws + off); off += (size_t)NN * 4;
    int*   incl = (int*)  (ws + off); off += (size_t)NN * 4;
    int*   bsum = (int*)  (ws + off); off += 128 * 4;
    int*   offs = (int*)  (ws + off); off += (size_t)(NN + 2) * 4;
    int*   cur  = (int*)  (ws + off); off += (size_t)NN * 4;
    off = (off + 15) & ~(size_t)15;
    int2*  csr  = (int2*) (ws + off); off += (size_t)NE * 8;

    const dim3 blk(256);
    const int  MT = (NN + 127) / 128;                  // 391 m-tiles
    const dim3 g128(1, MT), g256(2, MT);
    const int  EB = (NE + 255) / 256;
    const int  AGGB = (NN + 3) / 4;
    const int  MB64 = (NN + 63) / 64;

    // ---- CSR build
    hipMemsetAsync(deg, 0, (size_t)NN * 4, stream);
    hipMemsetAsync(cur, 0, (size_t)NN * 4, stream);
    hist_kernel<<<dim3(EB), blk, 0, stream>>>(ei, deg);
    scan1_kernel<<<dim3(SCAN_NB), dim3(SCAN_BS), 0, stream>>>(deg, incl, bsum);
    scan2_kernel<<<dim3(1), dim3(64), 0, stream>>>(bsum);
    scan3_kernel<<<dim3(SCAN_NB), dim3(SCAN_BS), 0, stream>>>(incl, deg, bsum, offs);
    scatter_kernel<<<dim3(EB), blk, 0, stream>>>(ei, offs, cur, csr);

    // ---- node-feature MLP
    gemm_mfma<true><<<g128, blk, 0, stream>>>(G,    64,  We1, 128, be1, bufA, 128, NN, 64);
    gemm_mfma<true><<<g128, blk, 0, stream>>>(bufA, 128, We2, 128, be2, bufC, 128, NN, 128);
    gemm_mfma<true><<<g128, blk, 0, stream>>>(bufC, 128, We3, 128, be3, bufA, 128, NN, 128);

    // ---- conv1: kqvs layout [k|s|q|v]
    gemm_mfma<false><<<g128, blk, 0, stream>>>(bufA, 128, c1_Wk, 128, c1_bk, bufB + 0,   512, NN, 128);
    gemm_mfma<false><<<g128, blk, 0, stream>>>(bufA, 128, c1_Ws, 128, c1_bs, bufB + 128, 512, NN, 128);
    gemm_mfma<false><<<g128, blk, 0, stream>>>(bufA, 128, c1_Wq, 128, c1_bq, bufB + 256, 512, NN, 128);
    gemm_mfma<false><<<g128, blk, 0, stream>>>(bufA, 128, c1_Wv, 128, c1_bv, bufB + 384, 512, NN, 128);
    conv_agg_kernel<<<dim3(AGGB), blk, 0, stream>>>(offs, csr, ea, c1_We, bufB, bufA);

    // ---- conv2
    gemm_mfma<false><<<g128, blk, 0, stream>>>(bufA, 128, c2_Wk, 128, c2_bk, bufB + 0,   512, NN, 128);
    gemm_mfma<false><<<g128, blk, 0, stream>>>(bufA, 128, c2_Ws, 128, c2_bs, bufB + 128, 512, NN, 128);
    gemm_mfma<false><<<g128, blk, 0, stream>>>(bufA, 128, c2_Wq, 128, c2_bq, bufB + 256, 512, NN, 128);
    gemm_mfma<false><<<g128, blk, 0, stream>>>(bufA, 128, c2_Wv, 128, c2_bv, bufB + 384, 512, NN, 128);
    conv_agg_kernel<<<dim3(AGGB), blk, 0, stream>>>(offs, csr, ea, c2_We, bufB, bufA);

    // ---- graph-level MLP
    gemm_mfma<true ><<<g128, blk, 0, stream>>>(bufA, 128, Wg1, 128, bg1, bufC, 128, NN, 128);
    gemm_mfma<false><<<g128, blk, 0, stream>>>(bufC, 128, Wg2, 128, bg2, bufA, 128, NN, 128);  // g2

    // ---- graph mean -> gvec
    hipMemsetAsync(gsum, 0, 128 * 4, stream);
    colsum_kernel<<<dim3(256), dim3(128), 0, stream>>>(bufA, gsum, NN);
    gvec_kernel<<<dim3(1), dim3(256), 0, stream>>>(gsum, Wl1, bl1, gvec, 1.f / NN);

    // ---- head
    gemm_mfma<true><<<g256, blk, 0, stream>>>(bufA, 128, Wl1, 256, gvec, bufB, 256, NN, 128);  // u1
    gemm_mfma<true><<<g128, blk, 0, stream>>>(bufB, 256, Wl2, 128, bl2, bufC, 128, NN, 256);   // u2
    head_out_kernel<<<dim3(MB64), blk, 0, stream>>>(bufC, Wl3, bl3, out, NN);
}